// Round 9
// baseline (872.623 us; speedup 1.0000x reference)
//
#include <hip/hip_runtime.h>

#define NN 100000
#define NNP 100096   // NN padded to multiple of 128 (GEMM tail reads)
#define NE 600000
#define KE 3
#define NL 3
#define D  128
#define EPS 1e-5f
#define NB 391       // ceil(NN/256) blocks per etype for the scan
#define NBKT 196     // buckets per etype: dst>>9 (512 nodes/bucket)
#define EPB 4096     // edges per block in bucket passes
#define NEB 147      // ceil(NE/EPB)
#define NSL 16       // stat slices (atomic contention spread)

typedef __attribute__((ext_vector_type(8))) short short8;
typedef __attribute__((ext_vector_type(4))) float floatx4;

__device__ __forceinline__ void atomic_add_f32(float* p, float v) { unsafeAtomicAdd(p, v); }

__device__ __forceinline__ float bf2f(unsigned int u16) {
    unsigned int v = u16 << 16;
    return __builtin_bit_cast(float, v);
}
__device__ __forceinline__ unsigned int f2bf(float f) {   // RNE
    unsigned int u = __builtin_bit_cast(unsigned int, f);
    u += 0x7FFFu + ((u >> 16) & 1u);
    return u >> 16;
}
__device__ __forceinline__ unsigned int pack2(float a, float b) {
    return f2bf(a) | (f2bf(b) << 16);
}

// ---- x (fp32) -> h (bf16); also zeros bucketTotal (saves a memset node) ----
__global__ void convert_x_kernel(const float* __restrict__ x, ushort* __restrict__ hbf,
                                 int* __restrict__ bucketTotal) {
    size_t i = (size_t)blockIdx.x * blockDim.x + threadIdx.x;
    if (i < KE * NBKT) bucketTotal[i] = 0;
    if (i >= (size_t)NN * D / 4) return;
    float4 v = *(const float4*)(x + i * 4);
    uint2 o;
    o.x = pack2(v.x, v.y);
    o.y = pack2(v.z, v.w);
    *(uint2*)(hbf + i * 4) = o;
}

// ---- W prep: Bt[l,k][n][kk] bf16; also zeros colsum/colsq (saves a memset node) ----
__global__ void wprep_kernel(const float* __restrict__ Ws, const float* __restrict__ Wn,
                             ushort* __restrict__ Bt, float* __restrict__ colstats) {
    int idx = blockIdx.x * blockDim.x + threadIdx.x;
    if (idx >= NL * KE * 128 * 256) return;
    if (idx < 2 * NL * NSL * D) colstats[idx] = 0.f;
    int lk  = idx >> 15;
    int rem = idx & 32767;
    int n   = rem >> 8;
    int kk  = rem & 255;
    float v = (kk < 128) ? Ws[(size_t)lk * 16384 + kk * 128 + n]
                         : Wn[(size_t)lk * 16384 + (kk - 128) * 128 + n];
    Bt[idx] = (ushort)f2bf(v);
}

// ---- merged BN finalize + fold (l < NL-1): all KE blocks compute sc/sh in LDS;
// block 0 publishes ss; each block folds its etype's W_self and bias ----
__global__ void finfold_kernel(const float* __restrict__ colsum, const float* __restrict__ colsq,
                               const float* __restrict__ gamma, const float* __restrict__ beta,
                               const float* __restrict__ Wsl, const float* __restrict__ bsrc,
                               float* __restrict__ ssl, ushort* __restrict__ Btl,
                               float* __restrict__ biasW) {
    __shared__ float sc_s[D], sh_s[D];
    const int k = blockIdx.x;      // KE
    const int c = threadIdx.x;     // 128
    float s = 0.f, q = 0.f;
    #pragma unroll
    for (int i = 0; i < NSL; ++i) { s += colsum[i * D + c]; q += colsq[i * D + c]; }
    float mu  = s * (1.0f / NN);
    float var = q * (1.0f / NN) - mu * mu;
    float sc  = gamma[c] * rsqrtf(var + EPS);
    float sh  = beta[c] - mu * sc;
    sc_s[c] = sc; sh_s[c] = sh;
    if (k == 0) { ssl[c] = sc; ssl[D + c] = sh; }
    __syncthreads();
    const float* W = Wsl + (size_t)k * D * D;
    ushort* B = Btl + (size_t)k * 32768;
    float acc = 0.f;
    #pragma unroll 4
    for (int kk = 0; kk < D; ++kk) {
        float w = W[kk * D + c];
        acc += sh_s[kk] * w;
        B[c * 256 + kk] = (ushort)f2bf(sc_s[kk] * w);
    }
    biasW[k * D + c] = bsrc[k * D + c] + acc;
}

// ==== CSR build: two-level bucket sort ====
__global__ void bucket_count_kernel(const int* __restrict__ dst,
                                    int* __restrict__ bucketTotal, int* __restrict__ blockBase) {
    const int blk = blockIdx.x;               // KE*NEB
    const int k = blk / NEB, cb = blk - k * NEB;
    __shared__ int hist[NBKT];
    for (int i = threadIdx.x; i < NBKT; i += 256) hist[i] = 0;
    __syncthreads();
    const int e0 = cb * EPB, e1 = min(e0 + EPB, NE);
    for (int e = e0 + threadIdx.x; e < e1; e += 256)
        atomicAdd(&hist[dst[(size_t)k * NE + e] >> 9], 1);
    __syncthreads();
    for (int i = threadIdx.x; i < NBKT; i += 256) {
        int c = hist[i];
        int base = c ? atomicAdd(&bucketTotal[k * NBKT + i], c) : 0;
        blockBase[(size_t)blk * NBKT + i] = base;
    }
}

__global__ void bucket_scan_kernel(const int* __restrict__ bucketTotal,
                                   int* __restrict__ bucketStart) {
    __shared__ int sd[1024];
    const int t = threadIdx.x;
    int v = (t < KE * NBKT) ? bucketTotal[t] : 0;
    sd[t] = v;
    __syncthreads();
    for (int off = 1; off < 1024; off <<= 1) {
        int u = (t >= off) ? sd[t - off] : 0;
        __syncthreads();
        sd[t] += u;
        __syncthreads();
    }
    if (t < KE * NBKT) bucketStart[t] = sd[t] - v;
}

__global__ void bucket_scatter_kernel(const int* __restrict__ src, const int* __restrict__ dst,
                                      const int* __restrict__ bucketStart,
                                      const int* __restrict__ blockBase,
                                      uint2* __restrict__ ebuf) {
    const int blk = blockIdx.x;
    const int k = blk / NEB, cb = blk - k * NEB;
    __shared__ int hist[NBKT], binoff[NBKT], cur[NBKT];
    __shared__ int sc[256];
    __shared__ uint2 stage[EPB];
    const int t = threadIdx.x;
    for (int i = t; i < NBKT; i += 256) hist[i] = 0;
    __syncthreads();
    const int e0 = cb * EPB, e1 = min(e0 + EPB, NE);
    for (int e = e0 + t; e < e1; e += 256)
        atomicAdd(&hist[dst[(size_t)k * NE + e] >> 9], 1);
    __syncthreads();
    int hv = (t < NBKT) ? hist[t] : 0;
    sc[t] = hv;
    __syncthreads();
    for (int off = 1; off < 256; off <<= 1) {
        int u = (t >= off) ? sc[t - off] : 0;
        __syncthreads();
        sc[t] += u;
        __syncthreads();
    }
    if (t < NBKT) { binoff[t] = sc[t] - hv; cur[t] = sc[t] - hv; }
    __syncthreads();
    for (int e = e0 + t; e < e1; e += 256) {
        int d = dst[(size_t)k * NE + e], s = src[(size_t)k * NE + e];
        int b = d >> 9;
        int p = atomicAdd(&cur[b], 1);
        stage[p] = make_uint2((unsigned)s, (unsigned)d);
    }
    __syncthreads();
    const int n = e1 - e0;
    for (int i = t; i < n; i += 256) {
        uint2 ed = stage[i];
        int b = (int)(ed.y >> 9);
        int pos = bucketStart[k * NBKT + b] + blockBase[(size_t)blk * NBKT + b] + (i - binoff[b]);
        ebuf[pos] = ed;
    }
}

// ---- per-bucket degree histogram; also emits the two 256-node bsum entries
// (replaces scan_a) ----
__global__ void bucket_deg_kernel(const uint2* __restrict__ ebuf,
                                  const int* __restrict__ bucketStart, int* __restrict__ degi,
                                  int* __restrict__ bsum) {
    const int blk = blockIdx.x;               // KE*NBKT
    const int k = blk / NBKT, b = blk - k * NBKT;
    __shared__ int cnt[512];
    const int t = threadIdx.x;
    for (int i = t; i < 512; i += 256) cnt[i] = 0;
    __syncthreads();
    const int s0 = bucketStart[blk];
    const int s1 = (blk + 1 < KE * NBKT) ? bucketStart[blk + 1] : KE * NE;
    for (int e = s0 + t; e < s1; e += 256)
        atomicAdd(&cnt[ebuf[e].y & 511], 1);
    __syncthreads();
    const int n0 = b << 9;
    for (int i = t; i < 512; i += 256) {
        int node = n0 + i;
        if (node < NN) degi[(size_t)k * NN + node] = cnt[i];
    }
    __syncthreads();
    // destructive tree reduce: cnt[0]=sum(0..255), cnt[256]=sum(256..511)
    for (int off = 128; off > 0; off >>= 1) {
        if (t < off) { cnt[t] += cnt[t + off]; cnt[256 + t] += cnt[256 + t + off]; }
        __syncthreads();
    }
    if (t == 0) {
        bsum[k * NB + 2 * b] = cnt[0];
        if (2 * b + 1 < NB) bsum[k * NB + 2 * b + 1] = cnt[256];
    }
}

__global__ void scan_b_kernel(int* __restrict__ bsum) {
    const int k = blockIdx.x;
    const int t = threadIdx.x;          // 512
    int v = (t < NB) ? bsum[k * NB + t] : 0;
    __shared__ int sd[512];
    sd[t] = v;
    __syncthreads();
    for (int off = 1; off < 512; off <<= 1) {
        int u = (t >= off) ? sd[t - off] : 0;
        __syncthreads();
        sd[t] += u;
        __syncthreads();
    }
    if (t < NB) bsum[k * NB + t] = sd[t] - v;
}

__global__ void scan_c_kernel(const int* __restrict__ degi, const int* __restrict__ bsum,
                              int* __restrict__ rowptr, float* __restrict__ invdeg) {
    const int b = blockIdx.x;
    const int k = b / NB, lb = b - k * NB;
    const int t = threadIdx.x;
    const int i = lb * 256 + t;
    int deg = (i < NN) ? degi[(size_t)k * NN + i] : 0;
    __shared__ int sd[256];
    sd[t] = deg;
    __syncthreads();
    for (int off = 1; off < 256; off <<= 1) {
        int u = (t >= off) ? sd[t - off] : 0;
        __syncthreads();
        sd[t] += u;
        __syncthreads();
    }
    int val = bsum[b] + sd[t] - deg;
    if (i < NN) {
        rowptr[(size_t)k * (NN + 1) + i] = val;
        invdeg[(size_t)k * NN + i] = 1.0f / (float)max(deg, 1);
    }
    if (i == NN) rowptr[(size_t)k * (NN + 1) + NN] = NE;
}

__global__ void bucket_fill_kernel(const uint2* __restrict__ ebuf,
                                   const int* __restrict__ bucketStart,
                                   const int* __restrict__ rowptr, int* __restrict__ csr) {
    const int blk = blockIdx.x;
    const int k = blk / NBKT, b = blk - k * NBKT;
    __shared__ int cur[512];
    const int n0 = b << 9;
    for (int i = threadIdx.x; i < 512; i += 256) {
        int node = n0 + i;
        cur[i] = (node < NN) ? rowptr[(size_t)k * (NN + 1) + node] : 0;
    }
    __syncthreads();
    const int s0 = bucketStart[blk];
    const int s1 = (blk + 1 < KE * NBKT) ? bucketStart[blk + 1] : KE * NE;
    for (int e = s0 + threadIdx.x; e < s1; e += 256) {
        uint2 ed = ebuf[e];
        int p = atomicAdd(&cur[ed.y & 511], 1);
        csr[(size_t)k * NE + p] = (int)ed.x;
    }
}

// ---- gather (all 3 etypes), bf16 rows, 16 lanes/node, 4 edges in flight ----
// affine!=0: apply BN of previous layer post-aggregation:
//   neigh_post = sc * mean(acc_src) + (deg>0 ? sh : 0)
__global__ void gather3_kernel(const ushort* __restrict__ hsrc, const int* __restrict__ csr,
                               const int* __restrict__ rowptr, const float* __restrict__ invdeg,
                               ushort* __restrict__ neigh, const float* __restrict__ ssl,
                               int affine) {
    int g = blockIdx.x * 16 + (threadIdx.x >> 4);
    if (g >= KE * NN) return;
    int k = g / NN, node = g - k * NN;
    const int q = (threadIdx.x & 15) * 8;
    const int* rp = rowptr + (size_t)k * (NN + 1) + node;
    const int* cs = csr + (size_t)k * NE;
    int beg = rp[0], end = rp[1];
    float f0=0,f1=0,f2=0,f3=0,f4=0,f5=0,f6=0,f7=0;
    int j = beg;
    for (; j + 4 <= end; j += 4) {
        int s0 = cs[j], s1 = cs[j + 1], s2 = cs[j + 2], s3 = cs[j + 3];
        uint4 a = *(const uint4*)(hsrc + (size_t)s0 * D + q);
        uint4 b = *(const uint4*)(hsrc + (size_t)s1 * D + q);
        uint4 c = *(const uint4*)(hsrc + (size_t)s2 * D + q);
        uint4 d = *(const uint4*)(hsrc + (size_t)s3 * D + q);
        f0 += bf2f(a.x & 0xffff) + bf2f(b.x & 0xffff) + bf2f(c.x & 0xffff) + bf2f(d.x & 0xffff);
        f1 += bf2f(a.x >> 16)    + bf2f(b.x >> 16)    + bf2f(c.x >> 16)    + bf2f(d.x >> 16);
        f2 += bf2f(a.y & 0xffff) + bf2f(b.y & 0xffff) + bf2f(c.y & 0xffff) + bf2f(d.y & 0xffff);
        f3 += bf2f(a.y >> 16)    + bf2f(b.y >> 16)    + bf2f(c.y >> 16)    + bf2f(d.y >> 16);
        f4 += bf2f(a.z & 0xffff) + bf2f(b.z & 0xffff) + bf2f(c.z & 0xffff) + bf2f(d.z & 0xffff);
        f5 += bf2f(a.z >> 16)    + bf2f(b.z >> 16)    + bf2f(c.z >> 16)    + bf2f(d.z >> 16);
        f6 += bf2f(a.w & 0xffff) + bf2f(b.w & 0xffff) + bf2f(c.w & 0xffff) + bf2f(d.w & 0xffff);
        f7 += bf2f(a.w >> 16)    + bf2f(b.w >> 16)    + bf2f(c.w >> 16)    + bf2f(d.w >> 16);
    }
    for (; j < end; ++j) {
        int s0 = cs[j];
        uint4 a = *(const uint4*)(hsrc + (size_t)s0 * D + q);
        f0 += bf2f(a.x & 0xffff); f1 += bf2f(a.x >> 16);
        f2 += bf2f(a.y & 0xffff); f3 += bf2f(a.y >> 16);
        f4 += bf2f(a.z & 0xffff); f5 += bf2f(a.z >> 16);
        f6 += bf2f(a.w & 0xffff); f7 += bf2f(a.w >> 16);
    }
    float iv = invdeg[g];
    float r0 = f0 * iv, r1 = f1 * iv, r2 = f2 * iv, r3 = f3 * iv;
    float r4 = f4 * iv, r5 = f5 * iv, r6 = f6 * iv, r7 = f7 * iv;
    if (affine) {
        float4 c0 = *(const float4*)(ssl + q);
        float4 c1 = *(const float4*)(ssl + q + 4);
        float4 h0 = *(const float4*)(ssl + D + q);
        float4 h1 = *(const float4*)(ssl + D + q + 4);
        float m = (end > beg) ? 1.0f : 0.0f;   // deg==0 -> neighbor feat is exactly 0
        r0 = r0 * c0.x + m * h0.x;  r1 = r1 * c0.y + m * h0.y;
        r2 = r2 * c0.z + m * h0.z;  r3 = r3 * c0.w + m * h0.w;
        r4 = r4 * c1.x + m * h1.x;  r5 = r5 * c1.y + m * h1.y;
        r6 = r6 * c1.z + m * h1.z;  r7 = r7 * c1.w + m * h1.w;
    }
    uint4 o;
    o.x = pack2(r0, r1);
    o.y = pack2(r2, r3);
    o.z = pack2(r4, r5);
    o.w = pack2(r6, r7);
    *(uint4*)(neigh + (size_t)k * NNP * D + (size_t)node * D + q) = o;
}

// ---- fused layer GEMM + column stats; BARRIER-FREE main loop ----
// 512 threads / 8 waves (2Mx4N), 128-row tile, per-wave output 64x32.
// A and B fragments are contiguous 16B runs in their global layouts (A: 256B rows,
// Bt: 512B [n][kk] rows) -> load DIRECTLY global->VGPR; no LDS, no __syncthreads in
// the K loop. Redundant reads (4x A across wn-waves, 2x B across wm) hit L1/L2.
// LDS only in the epilogue (Cs 32KB + red 8KB = 40KB -> 2 blocks/CU, 16 waves/CU).
// MFMA order = (etype k, chunk cc=c8>>1, ks=c8&1): identical to prior rounds ->
// bit-identical accumulation.
__global__ __launch_bounds__(512, 4)
void layer_gemm_kernel(const ushort* __restrict__ hself, const ushort* __restrict__ neigh,
                       const ushort* __restrict__ Bt,
                       const float* __restrict__ bias,
                       ushort* __restrict__ accb, int relu,
                       float* __restrict__ colsum, float* __restrict__ colsq) {
    __shared__ __align__(16) ushort Cs[128 * 128];     // 32 KB (epilogue only)
    __shared__ float red[2048];                        // 8 KB: redS [128][8] | redQ [128][8]
    const int tid  = threadIdx.x;
    const int wave = tid >> 6, lane = tid & 63;        // 8 waves
    const int wm = wave & 1, wn = wave >> 1;           // wm 0..1 (rows), wn 0..3 (cols)
    const int lrow = lane & 15, quad = lane >> 4;
    const int m0 = blockIdx.x * 128;
    const int qb = quad * 16;                          // byte offset of this lane's K-slice

    size_t aRow[4];                                    // A row byte offsets (256 B rows)
    #pragma unroll
    for (int im = 0; im < 4; ++im)
        aRow[im] = (size_t)(m0 + wm * 64 + im * 16 + lrow) * 256;
    size_t bRow[2];                                    // Bt row byte offsets (512 B rows)
    #pragma unroll
    for (int in = 0; in < 2; ++in)
        bRow[in] = (size_t)(wn * 32 + in * 16 + lrow) * 512;

    floatx4 tot[4][2];
    #pragma unroll
    for (int a = 0; a < 4; ++a)
        #pragma unroll
        for (int b = 0; b < 2; ++b)
            tot[a][b] = (floatx4){0.f, 0.f, 0.f, 0.f};

    for (int k = 0; k < KE; ++k) {
        const char* nB  = (const char*)(neigh + (size_t)k * NNP * D);
        const char* Btk = (const char*)Bt + (size_t)k * 65536;
        floatx4 o4[4][2];
        #pragma unroll
        for (int a = 0; a < 4; ++a)
            #pragma unroll
            for (int b = 0; b < 2; ++b)
                o4[a][b] = (floatx4){0.f, 0.f, 0.f, 0.f};
        // c8 = (cc<<1)|ks: cc 0,1 = self K-halves; 2,3 = neigh K-halves; ks = 32-wide sub
        #pragma unroll
        for (int c8 = 0; c8 < 8; ++c8) {
            const int part = c8 >> 2;                              // 0 self, 1 neigh
            const int off  = ((c8 >> 1) & 1) * 128 + (c8 & 1) * 64 + qb;
            const char* Ab = part ? nB : (const char*)hself;
            short8 af[4], bfr[2];
            #pragma unroll
            for (int im = 0; im < 4; ++im)
                af[im] = *(const short8*)(Ab + aRow[im] + off);
            #pragma unroll
            for (int in = 0; in < 2; ++in)
                bfr[in] = *(const short8*)(Btk + bRow[in] + part * 256 + off);
            #pragma unroll
            for (int im = 0; im < 4; ++im)
                #pragma unroll
                for (int in = 0; in < 2; ++in)
                    o4[im][in] = __builtin_amdgcn_mfma_f32_16x16x32_bf16(
                        af[im], bfr[in], o4[im][in], 0, 0, 0);
        }
        const float* bk = bias + k * D;
        float bv[2];
        #pragma unroll
        for (int in = 0; in < 2; ++in) bv[in] = bk[wn * 32 + in * 16 + lrow];
        #pragma unroll
        for (int im = 0; im < 4; ++im)
            #pragma unroll
            for (int in = 0; in < 2; ++in)
                #pragma unroll
                for (int r = 0; r < 4; ++r) {
                    float v = o4[im][in][r] + bv[in];
                    if (relu) v = fmaxf(v, 0.f);
                    tot[im][in][r] += v;
                }
    }

    // ---- fused column stats from fp32 registers (mask tail rows >= NN) ----
    float ls[2] = {0.f, 0.f}, lq[2] = {0.f, 0.f};
    #pragma unroll
    for (int im = 0; im < 4; ++im)
        #pragma unroll
        for (int r = 0; r < 4; ++r) {
            int row = m0 + wm * 64 + im * 16 + quad * 4 + r;
            bool ok = row < NN;
            #pragma unroll
            for (int in = 0; in < 2; ++in) {
                float v = ok ? tot[im][in][r] : 0.f;
                ls[in] += v;
                lq[in] += v * v;
            }
        }
    // write red + Cs together (no prior LDS use -> no barrier needed before)
    float* redS = red;             // [128][8]
    float* redQ = red + 1024;      // [128][8]
    #pragma unroll
    for (int in = 0; in < 2; ++in) {
        int col = wn * 32 + in * 16 + lrow;
        int slot = col * 8 + wm * 4 + quad;            // (wm,quad) unique per col
        redS[slot] = ls[in];
        redQ[slot] = lq[in];
    }
    #pragma unroll
    for (int im = 0; im < 4; ++im)
        #pragma unroll
        for (int r = 0; r < 4; ++r) {
            int rl = wm * 64 + im * 16 + quad * 4 + r;
            #pragma unroll
            for (int in = 0; in < 2; ++in)
                Cs[rl * 128 + wn * 32 + in * 16 + lrow] = (ushort)f2bf(tot[im][in][r]);
        }
    __syncthreads();               // the kernel's ONLY barrier
    if (tid < 128) {
        float s = 0.f, q = 0.f;
        #pragma unroll
        for (int i = 0; i < 8; ++i) { s += redS[tid * 8 + i]; q += redQ[tid * 8 + i]; }
        int slice = blockIdx.x & (NSL - 1);
        atomic_add_f32(&colsum[slice * D + tid], s);
        atomic_add_f32(&colsq[slice * D + tid], q);
    }
    #pragma unroll
    for (int jj = 0; jj < 4; ++jj) {
        int c8 = tid + jj * 512;           // uint4 index, 2048 total
        int rl = c8 >> 4;                  // 16 uint4 per 128-col row
        int cc = (c8 & 15) * 8;
        int row = m0 + rl;
        if (row < NN)
            *(uint4*)(accb + (size_t)row * D + cc) = *(const uint4*)(Cs + rl * 128 + cc);
    }
}

// ---- batchnorm finalize (last layer only; stats zeroed upfront by wprep) ----
__global__ void finalize_kernel(const float* __restrict__ colsum, const float* __restrict__ colsq,
                                const float* __restrict__ gamma, const float* __restrict__ beta,
                                float* __restrict__ ssl) {
    int c = threadIdx.x;  // 128
    float s = 0.f, q = 0.f;
    #pragma unroll
    for (int i = 0; i < NSL; ++i) { s += colsum[i * D + c]; q += colsq[i * D + c]; }
    float mu  = s * (1.0f / NN);
    float var = q * (1.0f / NN) - mu * mu;
    float sc  = gamma[c] * rsqrtf(var + EPS);
    ssl[c]     = sc;
    ssl[D + c] = beta[c] - mu * sc;
}

// ---- final BN apply (fp32 out), only for the last layer ----
__global__ void bn_kernel(const ushort* __restrict__ accb, const float* __restrict__ ssl,
                          float* __restrict__ out) {
    size_t i = (size_t)blockIdx.x * blockDim.x + threadIdx.x;
    if (i >= (size_t)NN * D / 4) return;
    int c4 = (int)(i & 31) << 2;
    uint2 a = *(const uint2*)(accb + i * 4);
    float4 v = {bf2f(a.x & 0xffff), bf2f(a.x >> 16), bf2f(a.y & 0xffff), bf2f(a.y >> 16)};
    float4 sc = *(const float4*)(ssl + c4);
    float4 sh = *(const float4*)(ssl + D + c4);
    float4 o;
    o.x = v.x * sc.x + sh.x;
    o.y = v.y * sc.y + sh.y;
    o.z = v.z * sc.z + sh.z;
    o.w = v.w * sc.w + sh.w;
    *(float4*)(out + i * 4) = o;
}

extern "C" void kernel_launch(void* const* d_in, const int* in_sizes, int n_in,
                              void* d_out, int out_size, void* d_ws, size_t ws_size,
                              hipStream_t stream) {
    const float* x       = (const float*)d_in[0];
    const int*   src     = (const int*)d_in[1];
    const int*   dst     = (const int*)d_in[2];
    const float* W_self  = (const float*)d_in[3];
    const float* W_neigh = (const float*)d_in[4];
    const float* bvec    = (const float*)d_in[5];
    const float* gamma   = (const float*)d_in[6];
    const float* beta    = (const float*)d_in[7];
    float* out = (float*)d_out;

    // ---- workspace layout ----
    ushort* accb   = (ushort*)d_ws;                       // NNP*D bf16 (pre-BN activations)
    float*  invdeg = (float*)(accb + (size_t)NNP * D);    // KE*NN
    float*  colsum = invdeg + (size_t)KE * NN;            // NL*NSL*D (per-layer slices)
    float*  colsq  = colsum + NL * NSL * D;               // NL*NSL*D
    float*  ss     = colsq + NL * NSL * D;                // NL*2*D (per-layer BN affine)
    float*  biasW  = ss + NL * 2 * D;                     // KE*D (folded bias)
    ushort* hbf    = (ushort*)(biasW + KE * D);           // NNP*D bf16 (x only)
    ushort* neigh  = hbf + (size_t)NNP * D;               // KE*NNP*D bf16
    ushort* Btw    = neigh + (size_t)KE * NNP * D;        // NL*KE*128*256 bf16
    int*    degi   = (int*)(Btw + (size_t)NL * KE * 128 * 256);  // KE*NN
    int*    rowptr = degi + (size_t)KE * NN;              // KE*(NN+1)
    int*    csr    = rowptr + (size_t)KE * (NN + 1);      // KE*NE
    int*    bsum   = csr + (size_t)KE * NE;               // KE*NB
    int*    bucketTotal = bsum + (size_t)KE * NB;         // KE*NBKT
    int*    bucketStart = bucketTotal + KE * NBKT;        // KE*NBKT
    int*    blockBase   = bucketStart + KE * NBKT;        // KE*NEB*NBKT
    uint2*  ebuf   = (uint2*)accb;  // aliases accb (14.4MB <= 25.6MB); CSR build precedes layer loop

    convert_x_kernel<<<(int)(((size_t)NN * D / 4 + 255) / 256), 256, 0, stream>>>(
        x, hbf, bucketTotal);
    wprep_kernel<<<(NL * KE * 128 * 256 + 255) / 256, 256, 0, stream>>>(
        W_self, W_neigh, Btw, colsum);

    bucket_count_kernel<<<KE * NEB, 256, 0, stream>>>(dst, bucketTotal, blockBase);
    bucket_scan_kernel<<<1, 1024, 0, stream>>>(bucketTotal, bucketStart);
    bucket_scatter_kernel<<<KE * NEB, 256, 0, stream>>>(src, dst, bucketStart, blockBase, ebuf);
    bucket_deg_kernel<<<KE * NBKT, 256, 0, stream>>>(ebuf, bucketStart, degi, bsum);
    scan_b_kernel<<<KE, 512, 0, stream>>>(bsum);
    scan_c_kernel<<<KE * NB, 256, 0, stream>>>(degi, bsum, rowptr, invdeg);
    bucket_fill_kernel<<<KE * NBKT, 256, 0, stream>>>(ebuf, bucketStart, rowptr, csr);

    for (int l = 0; l < NL; ++l) {
        int relu = (l < NL - 1) ? 1 : 0;
        const ushort* hsrc = (l == 0) ? hbf : accb;      // accb = pre-BN acts of layer l-1
        const float*  ssl  = ss + (size_t)(l ? l - 1 : 0) * 2 * D;
        gather3_kernel<<<(KE * NN + 15) / 16, 256, 0, stream>>>(
            hsrc, csr, rowptr, invdeg, neigh, ssl, l > 0);
        layer_gemm_kernel<<<NNP / 128, 512, 0, stream>>>(
            hsrc, neigh,
            Btw + (size_t)l * KE * 128 * 256,
            (l == 0) ? bvec : biasW,
            accb, relu,
            colsum + (size_t)l * NSL * D, colsq + (size_t)l * NSL * D);
        if (l + 1 < NL) {
            finfold_kernel<<<KE, 128, 0, stream>>>(
                colsum + (size_t)l * NSL * D, colsq + (size_t)l * NSL * D,
                gamma + (size_t)l * D, beta + (size_t)l * D,
                W_self + (size_t)(l + 1) * KE * D * D,
                bvec + (size_t)(l + 1) * KE * D,
                ss + (size_t)l * 2 * D,
                Btw + (size_t)(l + 1) * KE * 128 * 256,
                biasW);
        } else {
            finalize_kernel<<<1, 128, 0, stream>>>(
                colsum + (size_t)l * NSL * D, colsq + (size_t)l * NSL * D,
                gamma + (size_t)l * D, beta + (size_t)l * D, ss + (size_t)l * 2 * D);
        }
    }
    bn_kernel<<<(int)(((size_t)NN * D / 4 + 255) / 256), 256, 0, stream>>>(
        accb, ss + (size_t)(NL - 1) * 2 * D, out);
}

// Round 10
// 584.369 us; speedup vs baseline: 1.4933x; 1.4933x over previous
//
#include <hip/hip_runtime.h>

#define NN 100000
#define NNP 100096   // NN padded to multiple of 128 (GEMM tail reads)
#define NE 600000
#define KE 3
#define NL 3
#define D  128
#define EPS 1e-5f
#define NB 391       // ceil(NN/256) blocks per etype for the scan
#define NBKT 196     // buckets per etype: dst>>9 (512 nodes/bucket)
#define EPB 4096     // edges per block in bucket passes
#define NEB 147      // ceil(NE/EPB)
#define NSL 16       // stat slices (atomic contention spread)

typedef __attribute__((ext_vector_type(8))) short short8;
typedef __attribute__((ext_vector_type(4))) float floatx4;

__device__ __forceinline__ void atomic_add_f32(float* p, float v) { unsafeAtomicAdd(p, v); }

__device__ __forceinline__ float bf2f(unsigned int u16) {
    unsigned int v = u16 << 16;
    return __builtin_bit_cast(float, v);
}
__device__ __forceinline__ unsigned int f2bf(float f) {   // RNE
    unsigned int u = __builtin_bit_cast(unsigned int, f);
    u += 0x7FFFu + ((u >> 16) & 1u);
    return u >> 16;
}
__device__ __forceinline__ unsigned int pack2(float a, float b) {
    return f2bf(a) | (f2bf(b) << 16);
}

// async global->LDS, 16B per lane; LDS dest = wave-uniform base + lane*16
__device__ __forceinline__ void gload16(const void* g, void* l) {
    __builtin_amdgcn_global_load_lds(
        (const __attribute__((address_space(1))) void*)g,
        (__attribute__((address_space(3))) void*)l, 16, 0, 0);
}

// ---- x (fp32) -> h (bf16); also zeros bucketTotal (saves a memset node) ----
__global__ void convert_x_kernel(const float* __restrict__ x, ushort* __restrict__ hbf,
                                 int* __restrict__ bucketTotal) {
    size_t i = (size_t)blockIdx.x * blockDim.x + threadIdx.x;
    if (i < KE * NBKT) bucketTotal[i] = 0;
    if (i >= (size_t)NN * D / 4) return;
    float4 v = *(const float4*)(x + i * 4);
    uint2 o;
    o.x = pack2(v.x, v.y);
    o.y = pack2(v.z, v.w);
    *(uint2*)(hbf + i * 4) = o;
}

// ---- W prep: Bt[l,k][n][kk] bf16; also zeros colsum/colsq (saves a memset node) ----
__global__ void wprep_kernel(const float* __restrict__ Ws, const float* __restrict__ Wn,
                             ushort* __restrict__ Bt, float* __restrict__ colstats) {
    int idx = blockIdx.x * blockDim.x + threadIdx.x;
    if (idx >= NL * KE * 128 * 256) return;
    if (idx < 2 * NL * NSL * D) colstats[idx] = 0.f;
    int lk  = idx >> 15;
    int rem = idx & 32767;
    int n   = rem >> 8;
    int kk  = rem & 255;
    float v = (kk < 128) ? Ws[(size_t)lk * 16384 + kk * 128 + n]
                         : Wn[(size_t)lk * 16384 + (kk - 128) * 128 + n];
    Bt[idx] = (ushort)f2bf(v);
}

// ---- merged BN finalize + fold (l < NL-1): all KE blocks compute sc/sh in LDS;
// block 0 publishes ss; each block folds its etype's W_self and bias ----
__global__ void finfold_kernel(const float* __restrict__ colsum, const float* __restrict__ colsq,
                               const float* __restrict__ gamma, const float* __restrict__ beta,
                               const float* __restrict__ Wsl, const float* __restrict__ bsrc,
                               float* __restrict__ ssl, ushort* __restrict__ Btl,
                               float* __restrict__ biasW) {
    __shared__ float sc_s[D], sh_s[D];
    const int k = blockIdx.x;      // KE
    const int c = threadIdx.x;     // 128
    float s = 0.f, q = 0.f;
    #pragma unroll
    for (int i = 0; i < NSL; ++i) { s += colsum[i * D + c]; q += colsq[i * D + c]; }
    float mu  = s * (1.0f / NN);
    float var = q * (1.0f / NN) - mu * mu;
    float sc  = gamma[c] * rsqrtf(var + EPS);
    float sh  = beta[c] - mu * sc;
    sc_s[c] = sc; sh_s[c] = sh;
    if (k == 0) { ssl[c] = sc; ssl[D + c] = sh; }
    __syncthreads();
    const float* W = Wsl + (size_t)k * D * D;
    ushort* B = Btl + (size_t)k * 32768;
    float acc = 0.f;
    #pragma unroll 4
    for (int kk = 0; kk < D; ++kk) {
        float w = W[kk * D + c];
        acc += sh_s[kk] * w;
        B[c * 256 + kk] = (ushort)f2bf(sc_s[kk] * w);
    }
    biasW[k * D + c] = bsrc[k * D + c] + acc;
}

// ==== CSR build: two-level bucket sort ====
__global__ void bucket_count_kernel(const int* __restrict__ dst,
                                    int* __restrict__ bucketTotal, int* __restrict__ blockBase) {
    const int blk = blockIdx.x;               // KE*NEB
    const int k = blk / NEB, cb = blk - k * NEB;
    __shared__ int hist[NBKT];
    for (int i = threadIdx.x; i < NBKT; i += 256) hist[i] = 0;
    __syncthreads();
    const int e0 = cb * EPB, e1 = min(e0 + EPB, NE);
    for (int e = e0 + threadIdx.x; e < e1; e += 256)
        atomicAdd(&hist[dst[(size_t)k * NE + e] >> 9], 1);
    __syncthreads();
    for (int i = threadIdx.x; i < NBKT; i += 256) {
        int c = hist[i];
        int base = c ? atomicAdd(&bucketTotal[k * NBKT + i], c) : 0;
        blockBase[(size_t)blk * NBKT + i] = base;
    }
}

__global__ void bucket_scan_kernel(const int* __restrict__ bucketTotal,
                                   int* __restrict__ bucketStart) {
    __shared__ int sd[1024];
    const int t = threadIdx.x;
    int v = (t < KE * NBKT) ? bucketTotal[t] : 0;
    sd[t] = v;
    __syncthreads();
    for (int off = 1; off < 1024; off <<= 1) {
        int u = (t >= off) ? sd[t - off] : 0;
        __syncthreads();
        sd[t] += u;
        __syncthreads();
    }
    if (t < KE * NBKT) bucketStart[t] = sd[t] - v;
}

__global__ void bucket_scatter_kernel(const int* __restrict__ src, const int* __restrict__ dst,
                                      const int* __restrict__ bucketStart,
                                      const int* __restrict__ blockBase,
                                      uint2* __restrict__ ebuf) {
    const int blk = blockIdx.x;
    const int k = blk / NEB, cb = blk - k * NEB;
    __shared__ int hist[NBKT], binoff[NBKT], cur[NBKT];
    __shared__ int sc[256];
    __shared__ uint2 stage[EPB];
    const int t = threadIdx.x;
    for (int i = t; i < NBKT; i += 256) hist[i] = 0;
    __syncthreads();
    const int e0 = cb * EPB, e1 = min(e0 + EPB, NE);
    for (int e = e0 + t; e < e1; e += 256)
        atomicAdd(&hist[dst[(size_t)k * NE + e] >> 9], 1);
    __syncthreads();
    int hv = (t < NBKT) ? hist[t] : 0;
    sc[t] = hv;
    __syncthreads();
    for (int off = 1; off < 256; off <<= 1) {
        int u = (t >= off) ? sc[t - off] : 0;
        __syncthreads();
        sc[t] += u;
        __syncthreads();
    }
    if (t < NBKT) { binoff[t] = sc[t] - hv; cur[t] = sc[t] - hv; }
    __syncthreads();
    for (int e = e0 + t; e < e1; e += 256) {
        int d = dst[(size_t)k * NE + e], s = src[(size_t)k * NE + e];
        int b = d >> 9;
        int p = atomicAdd(&cur[b], 1);
        stage[p] = make_uint2((unsigned)s, (unsigned)d);
    }
    __syncthreads();
    const int n = e1 - e0;
    for (int i = t; i < n; i += 256) {
        uint2 ed = stage[i];
        int b = (int)(ed.y >> 9);
        int pos = bucketStart[k * NBKT + b] + blockBase[(size_t)blk * NBKT + b] + (i - binoff[b]);
        ebuf[pos] = ed;
    }
}

// ---- per-bucket degree histogram; also emits the two 256-node bsum entries
// (replaces scan_a) ----
__global__ void bucket_deg_kernel(const uint2* __restrict__ ebuf,
                                  const int* __restrict__ bucketStart, int* __restrict__ degi,
                                  int* __restrict__ bsum) {
    const int blk = blockIdx.x;               // KE*NBKT
    const int k = blk / NBKT, b = blk - k * NBKT;
    __shared__ int cnt[512];
    const int t = threadIdx.x;
    for (int i = t; i < 512; i += 256) cnt[i] = 0;
    __syncthreads();
    const int s0 = bucketStart[blk];
    const int s1 = (blk + 1 < KE * NBKT) ? bucketStart[blk + 1] : KE * NE;
    for (int e = s0 + t; e < s1; e += 256)
        atomicAdd(&cnt[ebuf[e].y & 511], 1);
    __syncthreads();
    const int n0 = b << 9;
    for (int i = t; i < 512; i += 256) {
        int node = n0 + i;
        if (node < NN) degi[(size_t)k * NN + node] = cnt[i];
    }
    __syncthreads();
    // destructive tree reduce: cnt[0]=sum(0..255), cnt[256]=sum(256..511)
    for (int off = 128; off > 0; off >>= 1) {
        if (t < off) { cnt[t] += cnt[t + off]; cnt[256 + t] += cnt[256 + t + off]; }
        __syncthreads();
    }
    if (t == 0) {
        bsum[k * NB + 2 * b] = cnt[0];
        if (2 * b + 1 < NB) bsum[k * NB + 2 * b + 1] = cnt[256];
    }
}

__global__ void scan_b_kernel(int* __restrict__ bsum) {
    const int k = blockIdx.x;
    const int t = threadIdx.x;          // 512
    int v = (t < NB) ? bsum[k * NB + t] : 0;
    __shared__ int sd[512];
    sd[t] = v;
    __syncthreads();
    for (int off = 1; off < 512; off <<= 1) {
        int u = (t >= off) ? sd[t - off] : 0;
        __syncthreads();
        sd[t] += u;
        __syncthreads();
    }
    if (t < NB) bsum[k * NB + t] = sd[t] - v;
}

__global__ void scan_c_kernel(const int* __restrict__ degi, const int* __restrict__ bsum,
                              int* __restrict__ rowptr, float* __restrict__ invdeg) {
    const int b = blockIdx.x;
    const int k = b / NB, lb = b - k * NB;
    const int t = threadIdx.x;
    const int i = lb * 256 + t;
    int deg = (i < NN) ? degi[(size_t)k * NN + i] : 0;
    __shared__ int sd[256];
    sd[t] = deg;
    __syncthreads();
    for (int off = 1; off < 256; off <<= 1) {
        int u = (t >= off) ? sd[t - off] : 0;
        __syncthreads();
        sd[t] += u;
        __syncthreads();
    }
    int val = bsum[b] + sd[t] - deg;
    if (i < NN) {
        rowptr[(size_t)k * (NN + 1) + i] = val;
        invdeg[(size_t)k * NN + i] = 1.0f / (float)max(deg, 1);
    }
    if (i == NN) rowptr[(size_t)k * (NN + 1) + NN] = NE;
}

__global__ void bucket_fill_kernel(const uint2* __restrict__ ebuf,
                                   const int* __restrict__ bucketStart,
                                   const int* __restrict__ rowptr, int* __restrict__ csr) {
    const int blk = blockIdx.x;
    const int k = blk / NBKT, b = blk - k * NBKT;
    __shared__ int cur[512];
    const int n0 = b << 9;
    for (int i = threadIdx.x; i < 512; i += 256) {
        int node = n0 + i;
        cur[i] = (node < NN) ? rowptr[(size_t)k * (NN + 1) + node] : 0;
    }
    __syncthreads();
    const int s0 = bucketStart[blk];
    const int s1 = (blk + 1 < KE * NBKT) ? bucketStart[blk + 1] : KE * NE;
    for (int e = s0 + threadIdx.x; e < s1; e += 256) {
        uint2 ed = ebuf[e];
        int p = atomicAdd(&cur[ed.y & 511], 1);
        csr[(size_t)k * NE + p] = (int)ed.x;
    }
}

// ---- gather (all 3 etypes), bf16 rows, 16 lanes/node, 4 edges in flight ----
// affine!=0: apply BN of previous layer post-aggregation:
//   neigh_post = sc * mean(acc_src) + (deg>0 ? sh : 0)
__global__ void gather3_kernel(const ushort* __restrict__ hsrc, const int* __restrict__ csr,
                               const int* __restrict__ rowptr, const float* __restrict__ invdeg,
                               ushort* __restrict__ neigh, const float* __restrict__ ssl,
                               int affine) {
    int g = blockIdx.x * 16 + (threadIdx.x >> 4);
    if (g >= KE * NN) return;
    int k = g / NN, node = g - k * NN;
    const int q = (threadIdx.x & 15) * 8;
    const int* rp = rowptr + (size_t)k * (NN + 1) + node;
    const int* cs = csr + (size_t)k * NE;
    int beg = rp[0], end = rp[1];
    float f0=0,f1=0,f2=0,f3=0,f4=0,f5=0,f6=0,f7=0;
    int j = beg;
    for (; j + 4 <= end; j += 4) {
        int s0 = cs[j], s1 = cs[j + 1], s2 = cs[j + 2], s3 = cs[j + 3];
        uint4 a = *(const uint4*)(hsrc + (size_t)s0 * D + q);
        uint4 b = *(const uint4*)(hsrc + (size_t)s1 * D + q);
        uint4 c = *(const uint4*)(hsrc + (size_t)s2 * D + q);
        uint4 d = *(const uint4*)(hsrc + (size_t)s3 * D + q);
        f0 += bf2f(a.x & 0xffff) + bf2f(b.x & 0xffff) + bf2f(c.x & 0xffff) + bf2f(d.x & 0xffff);
        f1 += bf2f(a.x >> 16)    + bf2f(b.x >> 16)    + bf2f(c.x >> 16)    + bf2f(d.x >> 16);
        f2 += bf2f(a.y & 0xffff) + bf2f(b.y & 0xffff) + bf2f(c.y & 0xffff) + bf2f(d.y & 0xffff);
        f3 += bf2f(a.y >> 16)    + bf2f(b.y >> 16)    + bf2f(c.y >> 16)    + bf2f(d.y >> 16);
        f4 += bf2f(a.z & 0xffff) + bf2f(b.z & 0xffff) + bf2f(c.z & 0xffff) + bf2f(d.z & 0xffff);
        f5 += bf2f(a.z >> 16)    + bf2f(b.z >> 16)    + bf2f(c.z >> 16)    + bf2f(d.z >> 16);
        f6 += bf2f(a.w & 0xffff) + bf2f(b.w & 0xffff) + bf2f(c.w & 0xffff) + bf2f(d.w & 0xffff);
        f7 += bf2f(a.w >> 16)    + bf2f(b.w >> 16)    + bf2f(c.w >> 16)    + bf2f(d.w >> 16);
    }
    for (; j < end; ++j) {
        int s0 = cs[j];
        uint4 a = *(const uint4*)(hsrc + (size_t)s0 * D + q);
        f0 += bf2f(a.x & 0xffff); f1 += bf2f(a.x >> 16);
        f2 += bf2f(a.y & 0xffff); f3 += bf2f(a.y >> 16);
        f4 += bf2f(a.z & 0xffff); f5 += bf2f(a.z >> 16);
        f6 += bf2f(a.w & 0xffff); f7 += bf2f(a.w >> 16);
    }
    float iv = invdeg[g];
    float r0 = f0 * iv, r1 = f1 * iv, r2 = f2 * iv, r3 = f3 * iv;
    float r4 = f4 * iv, r5 = f5 * iv, r6 = f6 * iv, r7 = f7 * iv;
    if (affine) {
        float4 c0 = *(const float4*)(ssl + q);
        float4 c1 = *(const float4*)(ssl + q + 4);
        float4 h0 = *(const float4*)(ssl + D + q);
        float4 h1 = *(const float4*)(ssl + D + q + 4);
        float m = (end > beg) ? 1.0f : 0.0f;   // deg==0 -> neighbor feat is exactly 0
        r0 = r0 * c0.x + m * h0.x;  r1 = r1 * c0.y + m * h0.y;
        r2 = r2 * c0.z + m * h0.z;  r3 = r3 * c0.w + m * h0.w;
        r4 = r4 * c1.x + m * h1.x;  r5 = r5 * c1.y + m * h1.y;
        r6 = r6 * c1.z + m * h1.z;  r7 = r7 * c1.w + m * h1.w;
    }
    uint4 o;
    o.x = pack2(r0, r1);
    o.y = pack2(r2, r3);
    o.z = pack2(r4, r5);
    o.w = pack2(r6, r7);
    *(uint4*)(neigh + (size_t)k * NNP * D + (size_t)node * D + q) = o;
}

// ---- fused layer GEMM + column stats; persistent self-A + 9-phase dbuf pipeline ----
// 512 threads / 8 waves (2Mx4N), 128-row tile, per-wave output 64x32.
// LDS: Asf 32K (self-A, staged ONCE) + Dst 2x32K dbuf = 96 KB -> 1 block/CU.
// Per etype 3 phases: pt0 {B-self both K-halves 32K} -> MFMA self kc0,kc1;
//                     pt1 {neighA kc0 16K + B-neigh kc0 16K} -> MFMA;
//                     pt2 {neighA kc1 + B-neigh kc1} -> MFMA, then bias/relu/tot.
// Self-tile traffic 1x instead of 3x (-51 MB/layer). MFMA order identical to prior
// rounds (self/kc0, self/kc1, neigh/kc0, neigh/kc1; ks inner) -> bit-identical.
// LDS swizzle (both-sides, rule #21): stored col-chunk cc (16B) of row r holds
// global chunk cc ^ (r&7); readers XOR the same.
__global__ __launch_bounds__(512, 2)
void layer_gemm_kernel(const ushort* __restrict__ hself, const ushort* __restrict__ neigh,
                       const ushort* __restrict__ Bt,
                       const float* __restrict__ bias,
                       ushort* __restrict__ accb, int relu,
                       float* __restrict__ colsum, float* __restrict__ colsq) {
    __shared__ __align__(16) ushort Asf[2][128][64];      // 32 KB persistent self-A
    __shared__ __align__(16) ushort Dst[2][2][128][64];   // 2 bufs x 32 KB
    const int tid  = threadIdx.x;
    const int wave = tid >> 6, lane = tid & 63;        // 8 waves
    const int wm = wave & 1, wn = wave >> 1;           // wm 0..1 (rows), wn 0..3 (cols)
    const int lrow = lane & 15, quad = lane >> 4;
    const int m0 = blockIdx.x * 128;
    // staging geometry (gload16): lane -> row = base + (lane>>3), col chunk = lane&7
    const int srow  = lane >> 3;
    const int scolb = ((lane & 7) ^ srow) << 4;        // pre-swizzled source col byte

#define STAGE(b, kk, pt)                                                                  \
    {                                                                                     \
        const char* Bsrc = (const char*)Bt + (size_t)(kk) * 65536;                        \
        char* Db = (char*)&Dst[b][0][0][0];                                               \
        if ((pt) == 0) {                                                                  \
            _Pragma("unroll")                                                             \
            for (int kc = 0; kc < 2; ++kc)                                                \
                _Pragma("unroll")                                                         \
                for (int i = 0; i < 2; ++i) {                                             \
                    int n = wave * 16 + i * 8 + srow;                                     \
                    gload16(Bsrc + (size_t)n * 512 + kc * 128 + scolb,                    \
                            Db + kc * 16384 + wave * 2048 + i * 1024);                    \
                }                                                                         \
        } else {                                                                          \
            const int kc = (pt) - 1;                                                      \
            const char* Asrc = (const char*)(neigh + (size_t)(kk) * NNP * D);             \
            _Pragma("unroll")                                                             \
            for (int i = 0; i < 2; ++i) {                                                 \
                int r = wave * 16 + i * 8 + srow;                                         \
                gload16(Asrc + (size_t)(m0 + r) * 256 + kc * 128 + scolb,                 \
                        Db + wave * 2048 + i * 1024);                                     \
                gload16(Bsrc + (size_t)r * 512 + 256 + kc * 128 + scolb,                  \
                        Db + 16384 + wave * 2048 + i * 1024);                             \
            }                                                                             \
        }                                                                                 \
    }

#define MFMA8(Abase, Bbase)                                                               \
    {                                                                                     \
        _Pragma("unroll")                                                                 \
        for (int ks = 0; ks < 2; ++ks) {                                                  \
            short8 af[4], bfr[2];                                                         \
            const int cb = ks * 64 + quad * 16;                                           \
            _Pragma("unroll")                                                             \
            for (int im = 0; im < 4; ++im) {                                              \
                int ra = wm * 64 + im * 16 + lrow;                                        \
                af[im] = *(const short8*)((Abase) + ra * 128 + (cb ^ ((ra & 7) << 4)));   \
            }                                                                             \
            _Pragma("unroll")                                                             \
            for (int in = 0; in < 2; ++in) {                                              \
                int rb = wn * 32 + in * 16 + lrow;                                        \
                bfr[in] = *(const short8*)((Bbase) + rb * 128 + (cb ^ ((rb & 7) << 4)));  \
            }                                                                             \
            _Pragma("unroll")                                                             \
            for (int im = 0; im < 4; ++im)                                                \
                _Pragma("unroll")                                                         \
                for (int in = 0; in < 2; ++in)                                            \
                    o4[im][in] = __builtin_amdgcn_mfma_f32_16x16x32_bf16(                 \
                        af[im], bfr[in], o4[im][in], 0, 0, 0);                            \
        }                                                                                 \
    }

    floatx4 tot[4][2], o4[4][2];
    #pragma unroll
    for (int a = 0; a < 4; ++a)
        #pragma unroll
        for (int b = 0; b < 2; ++b) {
            tot[a][b] = (floatx4){0.f, 0.f, 0.f, 0.f};
            o4[a][b]  = (floatx4){0.f, 0.f, 0.f, 0.f};
        }

    // prologue: stage persistent self-A (both K-halves) + phase 0 into buf 0
    {
        const char* Ab = (const char*)hself + (size_t)m0 * 256;
        #pragma unroll
        for (int kc = 0; kc < 2; ++kc)
            #pragma unroll
            for (int i = 0; i < 2; ++i)
                gload16(Ab + (size_t)(wave * 16 + i * 8 + srow) * 256 + kc * 128 + scolb,
                        (char*)Asf + kc * 16384 + wave * 2048 + i * 1024);
    }
    STAGE(0, 0, 0);

    int cur = 0;
    #pragma unroll
    for (int p = 0; p < 3 * KE; ++p) {
        __syncthreads();                       // buf[cur] (+Asf at p=0) staged
        if (p + 1 < 3 * KE) {
            const int pn = p + 1;
            STAGE(cur ^ 1, pn / 3, pn % 3);    // prefetch next phase (hides under MFMA)
        }
        const int pt = p % 3;
        const char* Db = (const char*)&Dst[cur][0][0][0];
        if (pt == 0) {
            MFMA8((const char*)Asf,         Db);            // self kc0
            MFMA8((const char*)Asf + 16384, Db + 16384);    // self kc1
        } else {
            MFMA8(Db, Db + 16384);                          // neigh kc(pt-1)
        }
        if (pt == 2) {                         // etype complete: bias + relu + accumulate
            const float* bk = bias + (p / 3) * D;
            float bv[2];
            #pragma unroll
            for (int in = 0; in < 2; ++in) bv[in] = bk[wn * 32 + in * 16 + lrow];
            #pragma unroll
            for (int im = 0; im < 4; ++im)
                #pragma unroll
                for (int in = 0; in < 2; ++in)
                    #pragma unroll
                    for (int r = 0; r < 4; ++r) {
                        float v = o4[im][in][r] + bv[in];
                        if (relu) v = fmaxf(v, 0.f);
                        tot[im][in][r] += v;
                        o4[im][in][r] = 0.f;
                    }
        }
        cur ^= 1;
    }
#undef STAGE
#undef MFMA8

    // ---- fused column stats from fp32 registers (mask tail rows >= NN) ----
    float ls[2] = {0.f, 0.f}, lq[2] = {0.f, 0.f};
    #pragma unroll
    for (int im = 0; im < 4; ++im)
        #pragma unroll
        for (int r = 0; r < 4; ++r) {
            int row = m0 + wm * 64 + im * 16 + quad * 4 + r;
            bool ok = row < NN;
            #pragma unroll
            for (int in = 0; in < 2; ++in) {
                float v = ok ? tot[im][in][r] : 0.f;
                ls[in] += v;
                lq[in] += v * v;
            }
        }
    // red -> Dst[1] (last read before final barrier); Cs -> Asf (last read p=6).
    // Final phase (p=8) reads Dst[0] only; all disjoint from epilogue writes.
    float* redS = (float*)&Dst[1][0][0][0];            // [128][8] floats
    float* redQ = redS + 1024;
    #pragma unroll
    for (int in = 0; in < 2; ++in) {
        int col = wn * 32 + in * 16 + lrow;
        int slot = col * 8 + wm * 4 + quad;            // (wm,quad) unique per col
        redS[slot] = ls[in];
        redQ[slot] = lq[in];
    }
    ushort* Cs = &Asf[0][0][0];                        // [128][128] ushort = 32 KB
    #pragma unroll
    for (int im = 0; im < 4; ++im)
        #pragma unroll
        for (int r = 0; r < 4; ++r) {
            int rl = wm * 64 + im * 16 + quad * 4 + r;
            #pragma unroll
            for (int in = 0; in < 2; ++in)
                Cs[rl * 128 + wn * 32 + in * 16 + lrow] = (ushort)f2bf(tot[im][in][r]);
        }
    __syncthreads();
    if (tid < 128) {
        float s = 0.f, q = 0.f;
        #pragma unroll
        for (int i = 0; i < 8; ++i) { s += redS[tid * 8 + i]; q += redQ[tid * 8 + i]; }
        int slice = blockIdx.x & (NSL - 1);
        atomic_add_f32(&colsum[slice * D + tid], s);
        atomic_add_f32(&colsq[slice * D + tid], q);
    }
    #pragma unroll
    for (int jj = 0; jj < 4; ++jj) {
        int c8 = tid + jj * 512;           // uint4 index, 2048 total
        int rl = c8 >> 4;                  // 16 uint4 per 128-col row
        int cc = (c8 & 15) * 8;
        int row = m0 + rl;
        if (row < NN)
            *(uint4*)(accb + (size_t)row * D + cc) = *(const uint4*)(Cs + rl * 128 + cc);
    }
}

// ---- batchnorm finalize (last layer only; stats zeroed upfront by wprep) ----
__global__ void finalize_kernel(const float* __restrict__ colsum, const float* __restrict__ colsq,
                                const float* __restrict__ gamma, const float* __restrict__ beta,
                                float* __restrict__ ssl) {
    int c = threadIdx.x;  // 128
    float s = 0.f, q = 0.f;
    #pragma unroll
    for (int i = 0; i < NSL; ++i) { s += colsum[i * D + c]; q += colsq[i * D + c]; }
    float mu  = s * (1.0f / NN);
    float var = q * (1.0f / NN) - mu * mu;
    float sc  = gamma[c] * rsqrtf(var + EPS);
    ssl[c]     = sc;
    ssl[D + c] = beta[c] - mu * sc;
}

// ---- final BN apply (fp32 out), only for the last layer ----
__global__ void bn_kernel(const ushort* __restrict__ accb, const float* __restrict__ ssl,
                          float* __restrict__ out) {
    size_t i = (size_t)blockIdx.x * blockDim.x + threadIdx.x;
    if (i >= (size_t)NN * D / 4) return;
    int c4 = (int)(i & 31) << 2;
    uint2 a = *(const uint2*)(accb + i * 4);
    float4 v = {bf2f(a.x & 0xffff), bf2f(a.x >> 16), bf2f(a.y & 0xffff), bf2f(a.y >> 16)};
    float4 sc = *(const float4*)(ssl + c4);
    float4 sh = *(const float4*)(ssl + D + c4);
    float4 o;
    o.x = v.x * sc.x + sh.x;
    o.y = v.y * sc.y + sh.y;
    o.z = v.z * sc.z + sh.z;
    o.w = v.w * sc.w + sh.w;
    *(float4*)(out + i * 4) = o;
}

extern "C" void kernel_launch(void* const* d_in, const int* in_sizes, int n_in,
                              void* d_out, int out_size, void* d_ws, size_t ws_size,
                              hipStream_t stream) {
    const float* x       = (const float*)d_in[0];
    const int*   src     = (const int*)d_in[1];
    const int*   dst     = (const int*)d_in[2];
    const float* W_self  = (const float*)d_in[3];
    const float* W_neigh = (const float*)d_in[4];
    const float* bvec    = (const float*)d_in[5];
    const float* gamma   = (const float*)d_in[6];
    const float* beta    = (const float*)d_in[7];
    float* out = (float*)d_out;

    // ---- workspace layout ----
    ushort* accb   = (ushort*)d_ws;                       // NNP*D bf16 (pre-BN activations)
    float*  invdeg = (float*)(accb + (size_t)NNP * D);    // KE*NN
    float*  colsum = invdeg + (size_t)KE * NN;            // NL*NSL*D (per-layer slices)
    float*  colsq  = colsum + NL * NSL * D;               // NL*NSL*D
    float*  ss     = colsq + NL * NSL * D;                // NL*2*D (per-layer BN affine)
    float*  biasW  = ss + NL * 2 * D;                     // KE*D (folded bias)
    ushort* hbf    = (ushort*)(biasW + KE * D);           // NNP*D bf16 (x only)
    ushort* neigh  = hbf + (size_t)NNP * D;               // KE*NNP*D bf16
    ushort* Btw    = neigh + (size_t)KE * NNP * D;        // NL*KE*128*256 bf16
    int*    degi   = (int*)(Btw + (size_t)NL * KE * 128 * 256);  // KE*NN
    int*    rowptr = degi + (size_t)KE * NN;              // KE*(NN+1)
    int*    csr    = rowptr + (size_t)KE * (NN + 1);      // KE*NE
    int*    bsum   = csr + (size_t)KE * NE;               // KE*NB
    int*    bucketTotal = bsum + (size_t)KE * NB;         // KE*NBKT
    int*    bucketStart = bucketTotal + KE * NBKT;        // KE*NBKT
    int*    blockBase   = bucketStart + KE * NBKT;        // KE*NEB*NBKT
    uint2*  ebuf   = (uint2*)accb;  // aliases accb (14.4MB <= 25.6MB); CSR build precedes layer loop

    convert_x_kernel<<<(int)(((size_t)NN * D / 4 + 255) / 256), 256, 0, stream>>>(
        x, hbf, bucketTotal);
    wprep_kernel<<<(NL * KE * 128 * 256 + 255) / 256, 256, 0, stream>>>(
        W_self, W_neigh, Btw, colsum);

    bucket_count_kernel<<<KE * NEB, 256, 0, stream>>>(dst, bucketTotal, blockBase);
    bucket_scan_kernel<<<1, 1024, 0, stream>>>(bucketTotal, bucketStart);
    bucket_scatter_kernel<<<KE * NEB, 256, 0, stream>>>(src, dst, bucketStart, blockBase, ebuf);
    bucket_deg_kernel<<<KE * NBKT, 256, 0, stream>>>(ebuf, bucketStart, degi, bsum);
    scan_b_kernel<<<KE, 512, 0, stream>>>(bsum);
    scan_c_kernel<<<KE * NB, 256, 0, stream>>>(degi, bsum, rowptr, invdeg);
    bucket_fill_kernel<<<KE * NBKT, 256, 0, stream>>>(ebuf, bucketStart, rowptr, csr);

    for (int l = 0; l < NL; ++l) {
        int relu = (l < NL - 1) ? 1 : 0;
        const ushort* hsrc = (l == 0) ? hbf : accb;      // accb = pre-BN acts of layer l-1
        const float*  ssl  = ss + (size_t)(l ? l - 1 : 0) * 2 * D;
        gather3_kernel<<<(KE * NN + 15) / 16, 256, 0, stream>>>(
            hsrc, csr, rowptr, invdeg, neigh, ssl, l > 0);
        layer_gemm_kernel<<<NNP / 128, 512, 0, stream>>>(
            hsrc, neigh,
            Btw + (size_t)l * KE * 128 * 256,
            (l == 0) ? bvec : biasW,
            accb, relu,
            colsum + (size_t)l * NSL * D, colsq + (size_t)l * NSL * D);
        if (l + 1 < NL) {
            finfold_kernel<<<KE, 128, 0, stream>>>(
                colsum + (size_t)l * NSL * D, colsq + (size_t)l * NSL * D,
                gamma + (size_t)l * D, beta + (size_t)l * D,
                W_self + (size_t)(l + 1) * KE * D * D,
                bvec + (size_t)(l + 1) * KE * D,
                ss + (size_t)l * 2 * D,
                Btw + (size_t)(l + 1) * KE * 128 * 256,
                biasW);
        } else {
            finalize_kernel<<<1, 128, 0, stream>>>(
                colsum + (size_t)l * NSL * D, colsq + (size_t)l * NSL * D,
                gamma + (size_t)l * D, beta + (size_t)l * D, ss + (size_t)l * 2 * D);
        }
    }
    bn_kernel<<<(int)(((size_t)NN * D / 4 + 255) / 256), 256, 0, stream>>>(
        accb, ss + (size_t)(NL - 1) * 2 * D, out);
}

// Round 11
// 548.646 us; speedup vs baseline: 1.5905x; 1.0651x over previous
//
#include <hip/hip_runtime.h>

#define NN 100000
#define NNP 100096   // NN padded to multiple of 128 (GEMM tail reads)
#define NE 600000
#define KE 3
#define NL 3
#define D  128
#define EPS 1e-5f
#define NB 391       // ceil(NN/256) blocks per etype for the scan
#define NBKT 196     // buckets per etype: dst>>9 (512 nodes/bucket)
#define EPB 4096     // edges per block in bucket passes
#define NEB 147      // ceil(NE/EPB)
#define NSL 16       // stat slices (atomic contention spread)

typedef __attribute__((ext_vector_type(8))) short short8;
typedef __attribute__((ext_vector_type(4))) float floatx4;

__device__ __forceinline__ void atomic_add_f32(float* p, float v) { unsafeAtomicAdd(p, v); }

__device__ __forceinline__ float bf2f(unsigned int u16) {
    unsigned int v = u16 << 16;
    return __builtin_bit_cast(float, v);
}
__device__ __forceinline__ unsigned int f2bf(float f) {   // RNE
    unsigned int u = __builtin_bit_cast(unsigned int, f);
    u += 0x7FFFu + ((u >> 16) & 1u);
    return u >> 16;
}
__device__ __forceinline__ unsigned int pack2(float a, float b) {
    return f2bf(a) | (f2bf(b) << 16);
}

// async global->LDS, 16B per lane; LDS dest = wave-uniform base + lane*16
__device__ __forceinline__ void gload16(const void* g, void* l) {
    __builtin_amdgcn_global_load_lds(
        (const __attribute__((address_space(1))) void*)g,
        (__attribute__((address_space(3))) void*)l, 16, 0, 0);
}

// ---- x (fp32) -> h (bf16); also zeros bucketTotal (saves a memset node) ----
__global__ void convert_x_kernel(const float* __restrict__ x, ushort* __restrict__ hbf,
                                 int* __restrict__ bucketTotal) {
    size_t i = (size_t)blockIdx.x * blockDim.x + threadIdx.x;
    if (i < KE * NBKT) bucketTotal[i] = 0;
    if (i >= (size_t)NN * D / 4) return;
    float4 v = *(const float4*)(x + i * 4);
    uint2 o;
    o.x = pack2(v.x, v.y);
    o.y = pack2(v.z, v.w);
    *(uint2*)(hbf + i * 4) = o;
}

// ---- W prep: Bt[l,k][n][kk] bf16; also zeros colsum/colsq (saves a memset node) ----
__global__ void wprep_kernel(const float* __restrict__ Ws, const float* __restrict__ Wn,
                             ushort* __restrict__ Bt, float* __restrict__ colstats) {
    int idx = blockIdx.x * blockDim.x + threadIdx.x;
    if (idx >= NL * KE * 128 * 256) return;
    if (idx < 2 * NL * NSL * D) colstats[idx] = 0.f;
    int lk  = idx >> 15;
    int rem = idx & 32767;
    int n   = rem >> 8;
    int kk  = rem & 255;
    float v = (kk < 128) ? Ws[(size_t)lk * 16384 + kk * 128 + n]
                         : Wn[(size_t)lk * 16384 + (kk - 128) * 128 + n];
    Bt[idx] = (ushort)f2bf(v);
}

// ---- merged BN finalize + fold (after layer 0): all KE blocks compute sc/sh in LDS;
// block 0 publishes ss; each block folds its etype's W_self and bias (for layer 1) ----
__global__ void finfold_kernel(const float* __restrict__ colsum, const float* __restrict__ colsq,
                               const float* __restrict__ gamma, const float* __restrict__ beta,
                               const float* __restrict__ Wsl, const float* __restrict__ bsrc,
                               float* __restrict__ ssl, ushort* __restrict__ Btl,
                               float* __restrict__ biasW) {
    __shared__ float sc_s[D], sh_s[D];
    const int k = blockIdx.x;      // KE
    const int c = threadIdx.x;     // 128
    float s = 0.f, q = 0.f;
    #pragma unroll
    for (int i = 0; i < NSL; ++i) { s += colsum[i * D + c]; q += colsq[i * D + c]; }
    float mu  = s * (1.0f / NN);
    float var = q * (1.0f / NN) - mu * mu;
    float sc  = gamma[c] * rsqrtf(var + EPS);
    float sh  = beta[c] - mu * sc;
    sc_s[c] = sc; sh_s[c] = sh;
    if (k == 0) { ssl[c] = sc; ssl[D + c] = sh; }
    __syncthreads();
    const float* W = Wsl + (size_t)k * D * D;
    ushort* B = Btl + (size_t)k * 32768;
    float acc = 0.f;
    #pragma unroll 4
    for (int kk = 0; kk < D; ++kk) {
        float w = W[kk * D + c];
        acc += sh_s[kk] * w;
        B[c * 256 + kk] = (ushort)f2bf(sc_s[kk] * w);
    }
    biasW[k * D + c] = bsrc[k * D + c] + acc;
}

// ---- BN finalize (layer 1) + MERGED fold for layer 2 (no relu -> self-GEMMs merge):
// Bsum[n][kk] = sum_k sc1[kk]*Ws2k[kk][n]; biasSum[n] = sum_k (b2k[n] + sh1@Ws2k[:,n]) ----
__global__ void finfold_merged_kernel(const float* __restrict__ colsum,
                                      const float* __restrict__ colsq,
                                      const float* __restrict__ gamma,
                                      const float* __restrict__ beta,
                                      const float* __restrict__ Wsl,   // W_self + 2*KE*D*D
                                      const float* __restrict__ bsrc,  // bvec + 2*KE*D
                                      float* __restrict__ ssl,         // ss + 1*2*D
                                      ushort* __restrict__ Bsum, float* __restrict__ biasSum) {
    __shared__ float sc_s[D], sh_s[D];
    const int c = threadIdx.x;     // 128
    float s = 0.f, q = 0.f;
    #pragma unroll
    for (int i = 0; i < NSL; ++i) { s += colsum[i * D + c]; q += colsq[i * D + c]; }
    float mu  = s * (1.0f / NN);
    float var = q * (1.0f / NN) - mu * mu;
    float sc  = gamma[c] * rsqrtf(var + EPS);
    float sh  = beta[c] - mu * sc;
    sc_s[c] = sc; sh_s[c] = sh;
    ssl[c] = sc; ssl[D + c] = sh;
    __syncthreads();
    float bacc = 0.f;
    #pragma unroll 2
    for (int kk = 0; kk < D; ++kk) {
        float wsum = 0.f;
        #pragma unroll
        for (int k = 0; k < KE; ++k) {
            float w = Wsl[(size_t)k * D * D + kk * D + c];
            wsum += sc_s[kk] * w;
            bacc += sh_s[kk] * w;
        }
        Bsum[c * 128 + kk] = (ushort)f2bf(wsum);
    }
    float bs = 0.f;
    #pragma unroll
    for (int k = 0; k < KE; ++k) bs += bsrc[k * D + c];
    biasSum[c] = bs + bacc;
}

// ==== CSR build: two-level bucket sort ====
__global__ void bucket_count_kernel(const int* __restrict__ dst,
                                    int* __restrict__ bucketTotal, int* __restrict__ blockBase) {
    const int blk = blockIdx.x;               // KE*NEB
    const int k = blk / NEB, cb = blk - k * NEB;
    __shared__ int hist[NBKT];
    for (int i = threadIdx.x; i < NBKT; i += 256) hist[i] = 0;
    __syncthreads();
    const int e0 = cb * EPB, e1 = min(e0 + EPB, NE);
    for (int e = e0 + threadIdx.x; e < e1; e += 256)
        atomicAdd(&hist[dst[(size_t)k * NE + e] >> 9], 1);
    __syncthreads();
    for (int i = threadIdx.x; i < NBKT; i += 256) {
        int c = hist[i];
        int base = c ? atomicAdd(&bucketTotal[k * NBKT + i], c) : 0;
        blockBase[(size_t)blk * NBKT + i] = base;
    }
}

__global__ void bucket_scan_kernel(const int* __restrict__ bucketTotal,
                                   int* __restrict__ bucketStart) {
    __shared__ int sd[1024];
    const int t = threadIdx.x;
    int v = (t < KE * NBKT) ? bucketTotal[t] : 0;
    sd[t] = v;
    __syncthreads();
    for (int off = 1; off < 1024; off <<= 1) {
        int u = (t >= off) ? sd[t - off] : 0;
        __syncthreads();
        sd[t] += u;
        __syncthreads();
    }
    if (t < KE * NBKT) bucketStart[t] = sd[t] - v;
}

__global__ void bucket_scatter_kernel(const int* __restrict__ src, const int* __restrict__ dst,
                                      const int* __restrict__ bucketStart,
                                      const int* __restrict__ blockBase,
                                      uint2* __restrict__ ebuf) {
    const int blk = blockIdx.x;
    const int k = blk / NEB, cb = blk - k * NEB;
    __shared__ int hist[NBKT], binoff[NBKT], cur[NBKT];
    __shared__ int sc[256];
    __shared__ uint2 stage[EPB];
    const int t = threadIdx.x;
    for (int i = t; i < NBKT; i += 256) hist[i] = 0;
    __syncthreads();
    const int e0 = cb * EPB, e1 = min(e0 + EPB, NE);
    for (int e = e0 + t; e < e1; e += 256)
        atomicAdd(&hist[dst[(size_t)k * NE + e] >> 9], 1);
    __syncthreads();
    int hv = (t < NBKT) ? hist[t] : 0;
    sc[t] = hv;
    __syncthreads();
    for (int off = 1; off < 256; off <<= 1) {
        int u = (t >= off) ? sc[t - off] : 0;
        __syncthreads();
        sc[t] += u;
        __syncthreads();
    }
    if (t < NBKT) { binoff[t] = sc[t] - hv; cur[t] = sc[t] - hv; }
    __syncthreads();
    for (int e = e0 + t; e < e1; e += 256) {
        int d = dst[(size_t)k * NE + e], s = src[(size_t)k * NE + e];
        int b = d >> 9;
        int p = atomicAdd(&cur[b], 1);
        stage[p] = make_uint2((unsigned)s, (unsigned)d);
    }
    __syncthreads();
    const int n = e1 - e0;
    for (int i = t; i < n; i += 256) {
        uint2 ed = stage[i];
        int b = (int)(ed.y >> 9);
        int pos = bucketStart[k * NBKT + b] + blockBase[(size_t)blk * NBKT + b] + (i - binoff[b]);
        ebuf[pos] = ed;
    }
}

// ---- per-bucket degree histogram; also emits the two 256-node bsum entries
// (replaces scan_a) ----
__global__ void bucket_deg_kernel(const uint2* __restrict__ ebuf,
                                  const int* __restrict__ bucketStart, int* __restrict__ degi,
                                  int* __restrict__ bsum) {
    const int blk = blockIdx.x;               // KE*NBKT
    const int k = blk / NBKT, b = blk - k * NBKT;
    __shared__ int cnt[512];
    const int t = threadIdx.x;
    for (int i = t; i < 512; i += 256) cnt[i] = 0;
    __syncthreads();
    const int s0 = bucketStart[blk];
    const int s1 = (blk + 1 < KE * NBKT) ? bucketStart[blk + 1] : KE * NE;
    for (int e = s0 + t; e < s1; e += 256)
        atomicAdd(&cnt[ebuf[e].y & 511], 1);
    __syncthreads();
    const int n0 = b << 9;
    for (int i = t; i < 512; i += 256) {
        int node = n0 + i;
        if (node < NN) degi[(size_t)k * NN + node] = cnt[i];
    }
    __syncthreads();
    // destructive tree reduce: cnt[0]=sum(0..255), cnt[256]=sum(256..511)
    for (int off = 128; off > 0; off >>= 1) {
        if (t < off) { cnt[t] += cnt[t + off]; cnt[256 + t] += cnt[256 + t + off]; }
        __syncthreads();
    }
    if (t == 0) {
        bsum[k * NB + 2 * b] = cnt[0];
        if (2 * b + 1 < NB) bsum[k * NB + 2 * b + 1] = cnt[256];
    }
}

__global__ void scan_b_kernel(int* __restrict__ bsum) {
    const int k = blockIdx.x;
    const int t = threadIdx.x;          // 512
    int v = (t < NB) ? bsum[k * NB + t] : 0;
    __shared__ int sd[512];
    sd[t] = v;
    __syncthreads();
    for (int off = 1; off < 512; off <<= 1) {
        int u = (t >= off) ? sd[t - off] : 0;
        __syncthreads();
        sd[t] += u;
        __syncthreads();
    }
    if (t < NB) bsum[k * NB + t] = sd[t] - v;
}

__global__ void scan_c_kernel(const int* __restrict__ degi, const int* __restrict__ bsum,
                              int* __restrict__ rowptr, float* __restrict__ invdeg) {
    const int b = blockIdx.x;
    const int k = b / NB, lb = b - k * NB;
    const int t = threadIdx.x;
    const int i = lb * 256 + t;
    int deg = (i < NN) ? degi[(size_t)k * NN + i] : 0;
    __shared__ int sd[256];
    sd[t] = deg;
    __syncthreads();
    for (int off = 1; off < 256; off <<= 1) {
        int u = (t >= off) ? sd[t - off] : 0;
        __syncthreads();
        sd[t] += u;
        __syncthreads();
    }
    int val = bsum[b] + sd[t] - deg;
    if (i < NN) {
        rowptr[(size_t)k * (NN + 1) + i] = val;
        invdeg[(size_t)k * NN + i] = 1.0f / (float)max(deg, 1);
    }
    if (i == NN) rowptr[(size_t)k * (NN + 1) + NN] = NE;
}

__global__ void bucket_fill_kernel(const uint2* __restrict__ ebuf,
                                   const int* __restrict__ bucketStart,
                                   const int* __restrict__ rowptr, int* __restrict__ csr) {
    const int blk = blockIdx.x;
    const int k = blk / NBKT, b = blk - k * NBKT;
    __shared__ int cur[512];
    const int n0 = b << 9;
    for (int i = threadIdx.x; i < 512; i += 256) {
        int node = n0 + i;
        cur[i] = (node < NN) ? rowptr[(size_t)k * (NN + 1) + node] : 0;
    }
    __syncthreads();
    const int s0 = bucketStart[blk];
    const int s1 = (blk + 1 < KE * NBKT) ? bucketStart[blk + 1] : KE * NE;
    for (int e = s0 + threadIdx.x; e < s1; e += 256) {
        uint2 ed = ebuf[e];
        int p = atomicAdd(&cur[ed.y & 511], 1);
        csr[(size_t)k * NE + p] = (int)ed.x;
    }
}

// ---- gather (all 3 etypes), bf16 rows, 16 lanes/node, 4 edges in flight ----
// affine!=0: apply BN of previous layer post-aggregation:
//   neigh_post = sc * mean(acc_src) + (deg>0 ? sh : 0)
__global__ void gather3_kernel(const ushort* __restrict__ hsrc, const int* __restrict__ csr,
                               const int* __restrict__ rowptr, const float* __restrict__ invdeg,
                               ushort* __restrict__ neigh, const float* __restrict__ ssl,
                               int affine) {
    int g = blockIdx.x * 16 + (threadIdx.x >> 4);
    if (g >= KE * NN) return;
    int k = g / NN, node = g - k * NN;
    const int q = (threadIdx.x & 15) * 8;
    const int* rp = rowptr + (size_t)k * (NN + 1) + node;
    const int* cs = csr + (size_t)k * NE;
    int beg = rp[0], end = rp[1];
    float f0=0,f1=0,f2=0,f3=0,f4=0,f5=0,f6=0,f7=0;
    int j = beg;
    for (; j + 4 <= end; j += 4) {
        int s0 = cs[j], s1 = cs[j + 1], s2 = cs[j + 2], s3 = cs[j + 3];
        uint4 a = *(const uint4*)(hsrc + (size_t)s0 * D + q);
        uint4 b = *(const uint4*)(hsrc + (size_t)s1 * D + q);
        uint4 c = *(const uint4*)(hsrc + (size_t)s2 * D + q);
        uint4 d = *(const uint4*)(hsrc + (size_t)s3 * D + q);
        f0 += bf2f(a.x & 0xffff) + bf2f(b.x & 0xffff) + bf2f(c.x & 0xffff) + bf2f(d.x & 0xffff);
        f1 += bf2f(a.x >> 16)    + bf2f(b.x >> 16)    + bf2f(c.x >> 16)    + bf2f(d.x >> 16);
        f2 += bf2f(a.y & 0xffff) + bf2f(b.y & 0xffff) + bf2f(c.y & 0xffff) + bf2f(d.y & 0xffff);
        f3 += bf2f(a.y >> 16)    + bf2f(b.y >> 16)    + bf2f(c.y >> 16)    + bf2f(d.y >> 16);
        f4 += bf2f(a.z & 0xffff) + bf2f(b.z & 0xffff) + bf2f(c.z & 0xffff) + bf2f(d.z & 0xffff);
        f5 += bf2f(a.z >> 16)    + bf2f(b.z >> 16)    + bf2f(c.z >> 16)    + bf2f(d.z >> 16);
        f6 += bf2f(a.w & 0xffff) + bf2f(b.w & 0xffff) + bf2f(c.w & 0xffff) + bf2f(d.w & 0xffff);
        f7 += bf2f(a.w >> 16)    + bf2f(b.w >> 16)    + bf2f(c.w >> 16)    + bf2f(d.w >> 16);
    }
    for (; j < end; ++j) {
        int s0 = cs[j];
        uint4 a = *(const uint4*)(hsrc + (size_t)s0 * D + q);
        f0 += bf2f(a.x & 0xffff); f1 += bf2f(a.x >> 16);
        f2 += bf2f(a.y & 0xffff); f3 += bf2f(a.y >> 16);
        f4 += bf2f(a.z & 0xffff); f5 += bf2f(a.z >> 16);
        f6 += bf2f(a.w & 0xffff); f7 += bf2f(a.w >> 16);
    }
    float iv = invdeg[g];
    float r0 = f0 * iv, r1 = f1 * iv, r2 = f2 * iv, r3 = f3 * iv;
    float r4 = f4 * iv, r5 = f5 * iv, r6 = f6 * iv, r7 = f7 * iv;
    if (affine) {
        float4 c0 = *(const float4*)(ssl + q);
        float4 c1 = *(const float4*)(ssl + q + 4);
        float4 h0 = *(const float4*)(ssl + D + q);
        float4 h1 = *(const float4*)(ssl + D + q + 4);
        float m = (end > beg) ? 1.0f : 0.0f;   // deg==0 -> neighbor feat is exactly 0
        r0 = r0 * c0.x + m * h0.x;  r1 = r1 * c0.y + m * h0.y;
        r2 = r2 * c0.z + m * h0.z;  r3 = r3 * c0.w + m * h0.w;
        r4 = r4 * c1.x + m * h1.x;  r5 = r5 * c1.y + m * h1.y;
        r6 = r6 * c1.z + m * h1.z;  r7 = r7 * c1.w + m * h1.w;
    }
    uint4 o;
    o.x = pack2(r0, r1);
    o.y = pack2(r2, r3);
    o.z = pack2(r4, r5);
    o.w = pack2(r6, r7);
    *(uint4*)(neigh + (size_t)k * NNP * D + (size_t)node * D + q) = o;
}

// ---- fused layer GEMM + column stats; double-buffered pipeline (round-8 structure) ----
// 512 threads / 8 waves (2Mx4N), 128-row tile, per-wave output 64x32.
// LDS: ST[2 bufs][A 16K | B 16K] = 64 KB -> 2 blocks/CU = 16 waves/CU.
// MERGED=0 (layers 0/1, per-etype relu): 12 phases, identical to round 8.
// MERGED=1 (layer 2, no relu): self-GEMMs merged via Bsum -> 8 phases
//   (self kc0, self kc1, then neigh[k] kc0/kc1 for k=0..2), bias once at end.
// LDS swizzle (both-sides, rule #21): stored col-chunk cc (16B) of row r holds
// global chunk cc ^ (r&7); readers XOR the same.
template <int MERGED>
__global__ __launch_bounds__(512, 4)
void layer_gemm_kernel(const ushort* __restrict__ hself, const ushort* __restrict__ neigh,
                       const ushort* __restrict__ Bt, const ushort* __restrict__ Bsum,
                       const float* __restrict__ bias,
                       ushort* __restrict__ accb, int relu,
                       float* __restrict__ colsum, float* __restrict__ colsq) {
    __shared__ __align__(16) ushort ST[2][2][128][64];   // [buf][A/B][row][col] = 64 KB
    const int tid  = threadIdx.x;
    const int wave = tid >> 6, lane = tid & 63;        // 8 waves
    const int wm = wave & 1, wn = wave >> 1;           // wm 0..1 (rows), wn 0..3 (cols)
    const int lrow = lane & 15, quad = lane >> 4;
    const int m0 = blockIdx.x * 128;
    // staging geometry (gload16): lane -> row = base + (lane>>3), col chunk = lane&7
    const int srow  = lane >> 3;
    const int scolb = ((lane & 7) ^ srow) << 4;        // pre-swizzled source col byte
    const int NPH = MERGED ? 2 + 2 * KE : 4 * KE;

#define STAGE(b, pp)                                                                     \
    {                                                                                    \
        const char* Asrc; const char* Bsrc; int aoff; int boff; int bstride;             \
        if (MERGED) {                                                                    \
            if ((pp) < 2) {                                                              \
                Asrc = (const char*)hself; aoff = (pp) * 128;                            \
                Bsrc = (const char*)Bsum;  boff = (pp) * 128; bstride = 256;             \
            } else {                                                                     \
                int kk2 = ((pp) - 2) >> 1, cc2 = ((pp) - 2) & 1;                         \
                Asrc = (const char*)(neigh + (size_t)kk2 * NNP * D); aoff = cc2 * 128;   \
                Bsrc = (const char*)Bt + (size_t)kk2 * 65536;                            \
                boff = 256 + cc2 * 128; bstride = 512;                                   \
            }                                                                            \
        } else {                                                                         \
            int kk2 = (pp) >> 2, cc2 = (pp) & 3;                                         \
            Asrc = (cc2 < 2) ? (const char*)hself                                        \
                             : (const char*)(neigh + (size_t)kk2 * NNP * D);             \
            aoff = (cc2 & 1) * 128;                                                      \
            Bsrc = (const char*)Bt + (size_t)kk2 * 65536;                                \
            boff = cc2 * 128; bstride = 512;                                             \
        }                                                                                \
        char* Adst = (char*)&ST[b][0][0][0];                                             \
        char* Bdst = (char*)&ST[b][1][0][0];                                             \
        _Pragma("unroll")                                                                \
        for (int i = 0; i < 2; ++i) {                                                    \
            int r = wave * 16 + i * 8 + srow;                                            \
            gload16(Asrc + (size_t)(m0 + r) * 256 + aoff + scolb,                        \
                    Adst + wave * 2048 + i * 1024);                                      \
            gload16(Bsrc + (size_t)r * bstride + boff + scolb,                           \
                    Bdst + wave * 2048 + i * 1024);                                      \
        }                                                                                \
    }

    floatx4 tot[4][2], o4[4][2];
    #pragma unroll
    for (int a = 0; a < 4; ++a)
        #pragma unroll
        for (int b = 0; b < 2; ++b) {
            tot[a][b] = (floatx4){0.f, 0.f, 0.f, 0.f};
            o4[a][b]  = (floatx4){0.f, 0.f, 0.f, 0.f};
        }

    // prologue: stage phase 0 into buf 0
    STAGE(0, 0);

    int cur = 0;
    #pragma unroll
    for (int p = 0; p < NPH; ++p) {
        __syncthreads();                       // buf[cur] staged; prior reads of buf[cur^1] done
        if (p + 1 < NPH) {
            STAGE(cur ^ 1, p + 1);             // prefetch next chunk (hides under MFMA)
        }
        const char* Ab = (const char*)&ST[cur][0][0][0];
        const char* Bb = (const char*)&ST[cur][1][0][0];
        #pragma unroll
        for (int ks = 0; ks < 2; ++ks) {
            short8 af[4], bfr[2];
            const int cb = ks * 64 + quad * 16;
            #pragma unroll
            for (int im = 0; im < 4; ++im) {
                int ra = wm * 64 + im * 16 + lrow;
                af[im] = *(const short8*)(Ab + ra * 128 + (cb ^ ((ra & 7) << 4)));
            }
            #pragma unroll
            for (int in = 0; in < 2; ++in) {
                int rb = wn * 32 + in * 16 + lrow;
                bfr[in] = *(const short8*)(Bb + rb * 128 + (cb ^ ((rb & 7) << 4)));
            }
            #pragma unroll
            for (int im = 0; im < 4; ++im)
                #pragma unroll
                for (int in = 0; in < 2; ++in)
                    o4[im][in] = __builtin_amdgcn_mfma_f32_16x16x32_bf16(
                        af[im], bfr[in], o4[im][in], 0, 0, 0);
        }
        if (!MERGED && (p & 3) == 3) {         // etype complete: bias + relu + accumulate
            const float* bk = bias + (p >> 2) * D;
            float bv[2];
            #pragma unroll
            for (int in = 0; in < 2; ++in) bv[in] = bk[wn * 32 + in * 16 + lrow];
            #pragma unroll
            for (int im = 0; im < 4; ++im)
                #pragma unroll
                for (int in = 0; in < 2; ++in)
                    #pragma unroll
                    for (int r = 0; r < 4; ++r) {
                        float v = o4[im][in][r] + bv[in];
                        if (relu) v = fmaxf(v, 0.f);
                        tot[im][in][r] += v;
                        o4[im][in][r] = 0.f;
                    }
        }
        cur ^= 1;
    }
#undef STAGE
    if (MERGED) {                              // single combined bias, no relu
        float bv[2];
        #pragma unroll
        for (int in = 0; in < 2; ++in) bv[in] = bias[wn * 32 + in * 16 + lrow];
        #pragma unroll
        for (int im = 0; im < 4; ++im)
            #pragma unroll
            for (int in = 0; in < 2; ++in)
                #pragma unroll
                for (int r = 0; r < 4; ++r)
                    tot[im][in][r] = o4[im][in][r] + bv[in];
    }

    // ---- fused column stats from fp32 registers (mask tail rows >= NN) ----
    float ls[2] = {0.f, 0.f}, lq[2] = {0.f, 0.f};
    #pragma unroll
    for (int im = 0; im < 4; ++im)
        #pragma unroll
        for (int r = 0; r < 4; ++r) {
            int row = m0 + wm * 64 + im * 16 + quad * 4 + r;
            bool ok = row < NN;
            #pragma unroll
            for (int in = 0; in < 2; ++in) {
                float v = ok ? tot[im][in][r] : 0.f;
                ls[in] += v;
                lq[in] += v * v;
            }
        }
    __syncthreads();                                   // all MFMA LDS reads done
    float* redS = (float*)&ST[1][0][0][0];             // [128][8] floats (8 KB, in buf1-A)
    float* redQ = redS + 1024;
    #pragma unroll
    for (int in = 0; in < 2; ++in) {
        int col = wn * 32 + in * 16 + lrow;
        int slot = col * 8 + wm * 4 + quad;            // (wm,quad) unique per col
        redS[slot] = ls[in];
        redQ[slot] = lq[in];
    }
    #pragma unroll
    for (int im = 0; im < 4; ++im)
        #pragma unroll
        for (int r = 0; r < 4; ++r) {
            int rl = wm * 64 + im * 16 + quad * 4 + r;
            #pragma unroll
            for (int in = 0; in < 2; ++in)
                ((ushort*)&ST[0][0][0][0])[rl * 128 + wn * 32 + in * 16 + lrow] =
                    (ushort)f2bf(tot[im][in][r]);
        }
    __syncthreads();
    if (tid < 128) {
        float s = 0.f, q = 0.f;
        #pragma unroll
        for (int i = 0; i < 8; ++i) { s += redS[tid * 8 + i]; q += redQ[tid * 8 + i]; }
        int slice = blockIdx.x & (NSL - 1);
        atomic_add_f32(&colsum[slice * D + tid], s);
        atomic_add_f32(&colsq[slice * D + tid], q);
    }
    const ushort* Cs = (const ushort*)&ST[0][0][0][0]; // [128][128] ushort = 32 KB
    #pragma unroll
    for (int jj = 0; jj < 4; ++jj) {
        int c8 = tid + jj * 512;           // uint4 index, 2048 total
        int rl = c8 >> 4;                  // 16 uint4 per 128-col row
        int cc = (c8 & 15) * 8;
        int row = m0 + rl;
        if (row < NN)
            *(uint4*)(accb + (size_t)row * D + cc) = *(const uint4*)(Cs + rl * 128 + cc);
    }
}

// ---- batchnorm finalize (last layer only; stats zeroed upfront by wprep) ----
__global__ void finalize_kernel(const float* __restrict__ colsum, const float* __restrict__ colsq,
                                const float* __restrict__ gamma, const float* __restrict__ beta,
                                float* __restrict__ ssl) {
    int c = threadIdx.x;  // 128
    float s = 0.f, q = 0.f;
    #pragma unroll
    for (int i = 0; i < NSL; ++i) { s += colsum[i * D + c]; q += colsq[i * D + c]; }
    float mu  = s * (1.0f / NN);
    float var = q * (1.0f / NN) - mu * mu;
    float sc  = gamma[c] * rsqrtf(var + EPS);
    ssl[c]     = sc;
    ssl[D + c] = beta[c] - mu * sc;
}

// ---- final BN apply (fp32 out), only for the last layer ----
__global__ void bn_kernel(const ushort* __restrict__ accb, const float* __restrict__ ssl,
                          float* __restrict__ out) {
    size_t i = (size_t)blockIdx.x * blockDim.x + threadIdx.x;
    if (i >= (size_t)NN * D / 4) return;
    int c4 = (int)(i & 31) << 2;
    uint2 a = *(const uint2*)(accb + i * 4);
    float4 v = {bf2f(a.x & 0xffff), bf2f(a.x >> 16), bf2f(a.y & 0xffff), bf2f(a.y >> 16)};
    float4 sc = *(const float4*)(ssl + c4);
    float4 sh = *(const float4*)(ssl + D + c4);
    float4 o;
    o.x = v.x * sc.x + sh.x;
    o.y = v.y * sc.y + sh.y;
    o.z = v.z * sc.z + sh.z;
    o.w = v.w * sc.w + sh.w;
    *(float4*)(out + i * 4) = o;
}

extern "C" void kernel_launch(void* const* d_in, const int* in_sizes, int n_in,
                              void* d_out, int out_size, void* d_ws, size_t ws_size,
                              hipStream_t stream) {
    const float* x       = (const float*)d_in[0];
    const int*   src     = (const int*)d_in[1];
    const int*   dst     = (const int*)d_in[2];
    const float* W_self  = (const float*)d_in[3];
    const float* W_neigh = (const float*)d_in[4];
    const float* bvec    = (const float*)d_in[5];
    const float* gamma   = (const float*)d_in[6];
    const float* beta    = (const float*)d_in[7];
    float* out = (float*)d_out;

    // ---- workspace layout ----
    ushort* accb   = (ushort*)d_ws;                       // NNP*D bf16 (pre-BN activations)
    float*  invdeg = (float*)(accb + (size_t)NNP * D);    // KE*NN
    float*  colsum = invdeg + (size_t)KE * NN;            // NL*NSL*D (per-layer slices)
    float*  colsq  = colsum + NL * NSL * D;               // NL*NSL*D
    float*  ss     = colsq + NL * NSL * D;                // NL*2*D (per-layer BN affine)
    float*  biasW  = ss + NL * 2 * D;                     // KE*D (folded bias, layer 1)
    float*  biasSum = biasW + KE * D;                     // D (merged bias, layer 2)
    ushort* Bsum   = (ushort*)(biasSum + D);              // 128x128 bf16 (merged self W, layer 2)
    ushort* hbf    = Bsum + 128 * 128;                    // NNP*D bf16 (x only)
    ushort* neigh  = hbf + (size_t)NNP * D;               // KE*NNP*D bf16
    ushort* Btw    = neigh + (size_t)KE * NNP * D;        // NL*KE*128*256 bf16
    int*    degi   = (int*)(Btw + (size_t)NL * KE * 128 * 256);  // KE*NN
    int*    rowptr = degi + (size_t)KE * NN;              // KE*(NN+1)
    int*    csr    = rowptr + (size_t)KE * (NN + 1);      // KE*NE
    int*    bsum   = csr + (size_t)KE * NE;               // KE*NB
    int*    bucketTotal = bsum + (size_t)KE * NB;         // KE*NBKT
    int*    bucketStart = bucketTotal + KE * NBKT;        // KE*NBKT
    int*    blockBase   = bucketStart + KE * NBKT;        // KE*NEB*NBKT
    uint2*  ebuf   = (uint2*)accb;  // aliases accb (14.4MB <= 25.6MB); CSR build precedes layer loop

    convert_x_kernel<<<(int)(((size_t)NN * D / 4 + 255) / 256), 256, 0, stream>>>(
        x, hbf, bucketTotal);
    wprep_kernel<<<(NL * KE * 128 * 256 + 255) / 256, 256, 0, stream>>>(
        W_self, W_neigh, Btw, colsum);

    bucket_count_kernel<<<KE * NEB, 256, 0, stream>>>(dst, bucketTotal, blockBase);
    bucket_scan_kernel<<<1, 1024, 0, stream>>>(bucketTotal, bucketStart);
    bucket_scatter_kernel<<<KE * NEB, 256, 0, stream>>>(src, dst, bucketStart, blockBase, ebuf);
    bucket_deg_kernel<<<KE * NBKT, 256, 0, stream>>>(ebuf, bucketStart, degi, bsum);
    scan_b_kernel<<<KE, 512, 0, stream>>>(bsum);
    scan_c_kernel<<<KE * NB, 256, 0, stream>>>(degi, bsum, rowptr, invdeg);
    bucket_fill_kernel<<<KE * NBKT, 256, 0, stream>>>(ebuf, bucketStart, rowptr, csr);

    for (int l = 0; l < NL; ++l) {
        int relu = (l < NL - 1) ? 1 : 0;
        const ushort* hsrc = (l == 0) ? hbf : accb;      // accb = pre-BN acts of layer l-1
        const float*  ssl  = ss + (size_t)(l ? l - 1 : 0) * 2 * D;
        gather3_kernel<<<(KE * NN + 15) / 16, 256, 0, stream>>>(
            hsrc, csr, rowptr, invdeg, neigh, ssl, l > 0);
        if (l < NL - 1) {
            layer_gemm_kernel<0><<<NNP / 128, 512, 0, stream>>>(
                hsrc, neigh,
                Btw + (size_t)l * KE * 128 * 256, Bsum,
                (l == 0) ? bvec : biasW,
                accb, relu,
                colsum + (size_t)l * NSL * D, colsq + (size_t)l * NSL * D);
        } else {
            layer_gemm_kernel<1><<<NNP / 128, 512, 0, stream>>>(
                hsrc, neigh,
                Btw + (size_t)l * KE * 128 * 256, Bsum,
                biasSum,
                accb, relu,
                colsum + (size_t)l * NSL * D, colsq + (size_t)l * NSL * D);
        }
        if (l == 0) {
            finfold_kernel<<<KE, 128, 0, stream>>>(
                colsum + (size_t)l * NSL * D, colsq + (size_t)l * NSL * D,
                gamma + (size_t)l * D, beta + (size_t)l * D,
                W_self + (size_t)(l + 1) * KE * D * D,
                bvec + (size_t)(l + 1) * KE * D,
                ss + (size_t)l * 2 * D,
                Btw + (size_t)(l + 1) * KE * 128 * 256,
                biasW);
        } else if (l == 1) {
            finfold_merged_kernel<<<1, 128, 0, stream>>>(
                colsum + (size_t)l * NSL * D, colsq + (size_t)l * NSL * D,
                gamma + (size_t)l * D, beta + (size_t)l * D,
                W_self + (size_t)(l + 1) * KE * D * D,
                bvec + (size_t)(l + 1) * KE * D,
                ss + (size_t)l * 2 * D,
                Bsum, biasSum);
        } else {
            finalize_kernel<<<1, 128, 0, stream>>>(
                colsum + (size_t)l * NSL * D, colsq + (size_t)l * NSL * D,
                gamma + (size_t)l * D, beta + (size_t)l * D, ss + (size_t)l * 2 * D);
        }
    }
    bn_kernel<<<(int)(((size_t)NN * D / 4 + 255) / 256), 256, 0, stream>>>(
        accb, ss + (size_t)(NL - 1) * 2 * D, out);
}